// Round 18
// baseline (81.190 us; speedup 1.0000x reference)
//
#include <hip/hip_runtime.h>

constexpr int B_   = 4;
constexpr int NL   = 8192;
constexpr int NH   = 2048;
constexpr int CH   = 256;
constexpr int CL   = 128;
constexpr int CIN  = 384;
constexpr int COUT = 256;

typedef _Float16 f16;
typedef _Float16 f16x8 __attribute__((ext_vector_type(8)));
typedef float    f32x4 __attribute__((ext_vector_type(4)));

// Fast branchless top-3 insert: 3 cmp + 5 cndmask (indices) + min/med3/med3
// (values) = 11 flat ops, dependency depth 2. Bit-equivalent to the
// sequential strict-< insert incl. earliest-index-wins on exact ties.
#define INS3F(d, h, B0, B1, B2, I0, I1, I2) do {                             \
    bool c0_ = (d) < (B0), c1_ = (d) < (B1), c2_ = (d) < (B2);               \
    int ni1_ = c0_ ? (I0) : (c1_ ? (h) : (I1));                              \
    int ni2_ = c1_ ? (I1) : (c2_ ? (h) : (I2));                              \
    I0 = c0_ ? (h) : (I0); I1 = ni1_; I2 = ni2_;                             \
    float nb1_ = __builtin_amdgcn_fmed3f(B0, B1, (d));                       \
    float nb2_ = __builtin_amdgcn_fmed3f(B1, B2, (d));                       \
    B0 = fminf(B0, (d)); B1 = nb1_; B2 = nb2_;                               \
} while (0)

// ---------------------------------------------------------------------------
// K1: prep.
//   [0,512):   fhT transpose (B,CH,NH) f32 -> (B,NH,CH) f16 (4 tiles each).
//   [512,896): W f32 -> f16.
// ---------------------------------------------------------------------------
__global__ __launch_bounds__(256) void prep_kernel(
    const float* __restrict__ feat_high, const float* __restrict__ Wm,
    f16* __restrict__ fhT, f16* __restrict__ Wh)
{
    __shared__ float tt[32][33];
    const int bid = blockIdx.x, tid = threadIdx.x;

    if (bid < 512) {
        const int tx = tid & 31, ty = tid >> 5;
        #pragma unroll
        for (int k = 0; k < 4; ++k) {
            const int u  = bid * 4 + k;            // 2048 tiles total
            const int ub = u >> 9, ut = u & 511;
            const int h0 = (ut & 63) * 32, c0 = (ut >> 6) * 32;
            #pragma unroll
            for (int pp = 0; pp < 4; ++pp)
                tt[ty + pp * 8][tx] =
                    feat_high[((size_t)ub * CH + c0 + ty + pp * 8) * NH + h0 + tx];
            __syncthreads();
            #pragma unroll
            for (int pp = 0; pp < 4; ++pp)
                fhT[((size_t)ub * NH + h0 + ty + pp * 8) * CH + c0 + tx] =
                    (f16)tt[tx][ty + pp * 8];
            __syncthreads();
        }
    } else {
        const int i = (bid - 512) * 256 + tid;     // 384 blocks
        Wh[i] = (f16)Wm[i];
    }
}

// ---------------------------------------------------------------------------
// K2: fused kNN + interp + GEMM. 256 blocks x 1024 thr (16 waves), 53.2 KB
// LDS. 128 low points per block, 2 QUERIES PER LANE -> each wave-uniform
// pts[h] broadcast serves 128 queries (ds_read count halved vs R17).
// Phase A: stage 2048 pts; wave w scans [w*128,+128) with 2 insert chains
//   per lane (queries lane, lane+64); barrier; md/mi alias dead pts region;
//   48-way w-ascending merge per point -> weights. Bit-identical d2 +
//   strict-< insert == reference top_k tie semantics.
// Phases B/C run twice (two 64-l halves sharing As[64][392]).
// ---------------------------------------------------------------------------
__global__ __launch_bounds__(1024, 4) void gemm_kernel(
    const float* __restrict__ xyz_low, const float* __restrict__ xyz_high,
    const float* __restrict__ feat_low, const f16* __restrict__ fhT,
    const f16* __restrict__ Wh, const float* __restrict__ bias,
    f16* __restrict__ yh, float* __restrict__ ps, float* __restrict__ psq)
{
    // As   [0,50176)      [64][392] f16 (gemm tile; Ys epilogue alias)
    // pts  [0,32768)      2048 float4   (dead after scan barrier)
    // md   [0,25088)      128*49 f32    (aliases pts; dead before As)
    // mi   [25088,37632)  128*49 u16    (aliases pts; dead before As)
    // idxL [50176,51712)  wL [51712,53248)   (live through gathers)
    __shared__ __align__(16) char smraw[53248];
    f16*            As   = (f16*)smraw;
    float4*         pts  = (float4*)smraw;
    float*          md   = (float*)smraw;
    unsigned short* mi   = (unsigned short*)(smraw + 25088);
    int*            idxL = (int*)(smraw + 50176);   // [3][128]
    float*          wL   = (float*)(smraw + 51712); // [3][128]

    const int bid = blockIdx.x, tid = threadIdx.x;
    const int b = bid >> 6, l0 = (bid & 63) * 128;
    const int lane = tid & 63, w = tid >> 6;       // w = 0..15

    // ---- phase A: stage pts + 2-query scan per wave-slice ----
    {
        const float* xh = xyz_high + (size_t)b * NH * 3;
        #pragma unroll
        for (int k = 0; k < 2; ++k) {
            const int h = k * 1024 + tid;
            float x = xh[h * 3], yy = xh[h * 3 + 1], z = xh[h * 3 + 2];
            pts[h] = make_float4(x, yy, z, x * x + yy * yy + z * z);
        }
    }
    __syncthreads();
    float a0 = 1e30f, a1 = 1e30f, a2 = 1e30f;
    float c0 = 1e30f, c1 = 1e30f, c2 = 1e30f;
    int ia0 = 0, ia1 = 0, ia2 = 0, ic0 = 0, ic1 = 0, ic2 = 0;
    {
        const float* xlA = xyz_low + ((size_t)b * NL + l0 + lane) * 3;
        const float* xlB = xyz_low + ((size_t)b * NL + l0 + 64 + lane) * 3;
        const float lxA = xlA[0], lyA = xlA[1], lzA = xlA[2];
        const float lxB = xlB[0], lyB = xlB[1], lzB = xlB[2];
        const float slA = lxA * lxA + lyA * lyA + lzA * lzA;
        const float slB = lxB * lxB + lyB * lyB + lzB * lzB;

        const int h0 = w * 128;
        #pragma unroll 8
        for (int i = 0; i < 128; ++i) {
            float4 pt = pts[h0 + i];               // wave-uniform broadcast
            float dA = fmaf(-2.0f, fmaf(lxA, pt.x, fmaf(lyA, pt.y, lzA * pt.z)),
                            slA + pt.w);
            float dB = fmaf(-2.0f, fmaf(lxB, pt.x, fmaf(lyB, pt.y, lzB * pt.z)),
                            slB + pt.w);
            INS3F(dA, h0 + i, a0, a1, a2, ia0, ia1, ia2);
            INS3F(dB, h0 + i, c0, c1, c2, ic0, ic1, ic2);
        }
    }
    __syncthreads();   // all pts reads done -> md/mi may alias pts
    {
        const int cbA = lane * 49 + w * 3;
        const int cbB = (64 + lane) * 49 + w * 3;
        md[cbA] = a0;     mi[cbA] = (unsigned short)ia0;
        md[cbA + 1] = a1; mi[cbA + 1] = (unsigned short)ia1;
        md[cbA + 2] = a2; mi[cbA + 2] = (unsigned short)ia2;
        md[cbB] = c0;     mi[cbB] = (unsigned short)ic0;
        md[cbB + 1] = c1; mi[cbB + 1] = (unsigned short)ic1;
        md[cbB + 2] = c2; mi[cbB + 2] = (unsigned short)ic2;
    }
    __syncthreads();

    if (tid < 128) {  // 48-way merge in w-ascending (= h-ascending) order
        float e0 = 1e30f, e1 = 1e30f, e2 = 1e30f;
        int j0 = 0, j1 = 0, j2 = 0;
        #pragma unroll
        for (int q = 0; q < 48; ++q) {
            float d = md[tid * 49 + q];
            int  ii = mi[tid * 49 + q];
            INS3F(d, ii, e0, e1, e2, j0, j1, j2);
        }
        float d0 = sqrtf(fmaxf(e0, 0.0f));
        float d1 = sqrtf(fmaxf(e1, 0.0f));
        float d2f = sqrtf(fmaxf(e2, 0.0f));
        float iw0 = 1.0f / fmaxf(d0, 1e-8f);
        float iw1 = 1.0f / fmaxf(d1, 1e-8f);
        float iw2 = 1.0f / fmaxf(d2f, 1e-8f);
        float sum = iw0 + iw1 + iw2;
        idxL[tid] = j0; idxL[128 + tid] = j1; idxL[256 + tid] = j2;
        wL[tid] = iw0 / sum; wL[128 + tid] = iw1 / sum; wL[256 + tid] = iw2 / sum;
    }
    __syncthreads();

    const int kb = (lane >> 4) * 8;
    const int r  = lane & 15;
    const int r4 = (lane >> 4) * 4, cl = lane & 15;

    #pragma unroll
    for (int half = 0; half < 2; ++half) {
        const int l0h = l0 + half * 64;

        // ---- phase B: interp gather + feat_low staging ----
        {
            const int p = tid >> 4, q = tid & 15;  // 64 pts x 16-ch chunks
            const int lp = half * 64 + p;
            const int j0 = idxL[lp], j1 = idxL[128 + lp], j2 = idxL[256 + lp];
            const float u0 = wL[lp], u1 = wL[128 + lp], u2 = wL[256 + lp];
            const f16* r0 = fhT + ((size_t)b * NH + j0) * CH + q * 16;
            const f16* r1 = fhT + ((size_t)b * NH + j1) * CH + q * 16;
            const f16* r2 = fhT + ((size_t)b * NH + j2) * CH + q * 16;
            #pragma unroll
            for (int j = 0; j < 2; ++j) {
                f16x8 v0 = *(const f16x8*)(r0 + j * 8);
                f16x8 v1 = *(const f16x8*)(r1 + j * 8);
                f16x8 v2 = *(const f16x8*)(r2 + j * 8);
                f16x8 o;
                #pragma unroll
                for (int e = 0; e < 8; ++e)
                    o[e] = (f16)(u0 * (float)v0[e] + u1 * (float)v1[e]
                                 + u2 * (float)v2[e]);
                *(f16x8*)&As[p * 392 + q * 16 + j * 8] = o;
            }
            const int l = tid & 63, cq = tid >> 6; // cq = 0..15, 8 ch each
            const float* flb = feat_low + ((size_t)b * CL + cq * 8) * NL + l0h + l;
            f16 tmp[8];
            #pragma unroll
            for (int i = 0; i < 8; ++i)
                tmp[i] = (f16)flb[(size_t)i * NL];
            *(f16x8*)&As[l * 392 + 256 + cq * 8] = *(const f16x8*)&tmp[0];
        }
        __syncthreads();

        // ---- phase C: MFMA K-loop (wave owns 16 o-rows) ----
        f32x4 acc[4] = {};
        #pragma unroll
        for (int kt = 0; kt < 12; ++kt) {
            const int k0 = kt * 32;
            f16x8 a = *(const f16x8*)&Wh[(size_t)(w * 16 + r) * CIN + k0 + kb];
            f16x8 bb[4];
            #pragma unroll
            for (int ni = 0; ni < 4; ++ni)
                bb[ni] = *(const f16x8*)&As[(ni * 16 + r) * 392 + k0 + kb];
            #pragma unroll
            for (int ni = 0; ni < 4; ++ni)
                acc[ni] = __builtin_amdgcn_mfma_f32_16x16x32_f16(
                    a, bb[ni], acc[ni], 0, 0, 0);
        }

        // bias + BN partials (bidx = bid*2 + half in [0,512))
        #pragma unroll
        for (int j = 0; j < 4; ++j) {
            const int o = w * 16 + r4 + j;
            const float bi = bias[o];
            float s = 0.0f, sq = 0.0f;
            #pragma unroll
            for (int ni = 0; ni < 4; ++ni) {
                acc[ni][j] += bi;
                float v = acc[ni][j];
                s += v; sq += v * v;
            }
            #pragma unroll
            for (int m = 1; m < 16; m <<= 1) {
                s  += __shfl_xor(s, m);
                sq += __shfl_xor(sq, m);
            }
            if (cl == 0) {
                ps [o * 512 + bid * 2 + half] = s;
                psq[o * 512 + bid * 2 + half] = sq;
            }
        }
        __syncthreads();   // all As reads done -> safe to alias with Ys

        f16* Ys = (f16*)smraw;         // [256][72] f16 = 36864 B
        #pragma unroll
        for (int j = 0; j < 4; ++j) {
            const int o = w * 16 + r4 + j;
            #pragma unroll
            for (int ni = 0; ni < 4; ++ni)
                Ys[o * 72 + cl + ni * 16] = (f16)acc[ni][j];
        }
        __syncthreads();
        {   // store: 4 threads per o-row -> 128B contiguous per row
            const int o = tid >> 2, qtr = tid & 3;
            f16* dst = yh + ((size_t)b * COUT + o) * NL + l0h + qtr * 16;
            *(f16x8*)(dst)     = *(const f16x8*)&Ys[o * 72 + qtr * 16];
            *(f16x8*)(dst + 8) = *(const f16x8*)&Ys[o * 72 + qtr * 16 + 8];
        }
        __syncthreads();   // Ys reads done before next half rewrites As
    }
}

// ---------------------------------------------------------------------------
// K3: fused BN stats + apply + ReLU. Grid (COUT, B_): each block reduces its
// channel's 512 partials (deterministic, redundant across b-blocks) then
// applies to its (b,o) row of 8192.
// ---------------------------------------------------------------------------
__global__ __launch_bounds__(256) void stats_apply_kernel(
    const float* __restrict__ ps, const float* __restrict__ psq,
    const f16* __restrict__ yh,
    const float* __restrict__ gamma, const float* __restrict__ beta,
    float* __restrict__ y)
{
    const int o = blockIdx.x, b = blockIdx.y, tid = threadIdx.x;
    const int w = tid >> 6, lane = tid & 63;

    float s = ps[o * 512 + tid] + ps[o * 512 + 256 + tid];
    float q = psq[o * 512 + tid] + psq[o * 512 + 256 + tid];
    #pragma unroll
    for (int m = 32; m > 0; m >>= 1) {
        s += __shfl_down(s, m);
        q += __shfl_down(q, m);
    }
    __shared__ float red[8];
    if (lane == 0) { red[w] = s; red[4 + w] = q; }
    __syncthreads();
    s = red[0] + red[1] + red[2] + red[3];
    q = red[4] + red[5] + red[6] + red[7];
    const float n  = (float)(B_ * NL);
    const float mu = s / n;
    const float rs = rsqrtf(q / n - mu * mu + 1e-5f);
    const float g  = gamma[o], be = beta[o];

    const f16* src = yh + ((size_t)b * COUT + o) * NL;
    float*     dst = y  + ((size_t)b * COUT + o) * NL;
    #pragma unroll
    for (int it = 0; it < 4; ++it) {
        const int base = it * 2048 + tid * 8;
        f16x8 v = *(const f16x8*)(src + base);
        float4 o1, o2;
        o1.x = fmaxf(fmaf(g, ((float)v[0] - mu) * rs, be), 0.0f);
        o1.y = fmaxf(fmaf(g, ((float)v[1] - mu) * rs, be), 0.0f);
        o1.z = fmaxf(fmaf(g, ((float)v[2] - mu) * rs, be), 0.0f);
        o1.w = fmaxf(fmaf(g, ((float)v[3] - mu) * rs, be), 0.0f);
        o2.x = fmaxf(fmaf(g, ((float)v[4] - mu) * rs, be), 0.0f);
        o2.y = fmaxf(fmaf(g, ((float)v[5] - mu) * rs, be), 0.0f);
        o2.z = fmaxf(fmaf(g, ((float)v[6] - mu) * rs, be), 0.0f);
        o2.w = fmaxf(fmaf(g, ((float)v[7] - mu) * rs, be), 0.0f);
        *(float4*)(dst + base)     = o1;
        *(float4*)(dst + base + 4) = o2;
    }
}

// ---------------------------------------------------------------------------
extern "C" void kernel_launch(void* const* d_in, const int* in_sizes, int n_in,
                              void* d_out, int out_size, void* d_ws, size_t ws_size,
                              hipStream_t stream)
{
    const float* xyz_low   = (const float*)d_in[0];
    const float* xyz_high  = (const float*)d_in[1];
    const float* feat_low  = (const float*)d_in[2];
    const float* feat_high = (const float*)d_in[3];
    const float* Wm        = (const float*)d_in[4];
    const float* bias      = (const float*)d_in[5];
    const float* gamma     = (const float*)d_in[6];
    const float* beta      = (const float*)d_in[7];
    float* y = (float*)d_out;

    float* ps   = (float*)d_ws;                        // 256*512 f32
    float* psq  = ps + (size_t)COUT * 512;             // 256*512 f32
    f16*   Wh   = (f16*)(psq + (size_t)COUT * 512);    // 256*384 f16
    f16*   fhT  = Wh + (size_t)COUT * CIN;             // 4*2048*256 f16 (4.2MB)
    f16*   yh   = fhT + (size_t)B_ * NH * CH;          // 4*256*8192 f16 (16.8MB)

    prep_kernel<<<896, 256, 0, stream>>>(feat_high, Wm, fhT, Wh);
    gemm_kernel<<<256, 1024, 0, stream>>>(
        xyz_low, xyz_high, feat_low, fhT, Wh, bias, yh, ps, psq);
    stats_apply_kernel<<<dim3(COUT, B_), 256, 0, stream>>>(
        ps, psq, yh, gamma, beta, y);
}

// Round 19
// 73.411 us; speedup vs baseline: 1.1060x; 1.1060x over previous
//
#include <hip/hip_runtime.h>

constexpr int B_   = 4;
constexpr int NL   = 8192;
constexpr int NH   = 2048;
constexpr int CH   = 256;
constexpr int CL   = 128;
constexpr int CIN  = 384;
constexpr int COUT = 256;

typedef _Float16 f16;
typedef _Float16 f16x8 __attribute__((ext_vector_type(8)));
typedef float    f32x4 __attribute__((ext_vector_type(4)));

// Fast branchless top-3 insert: 3 cmp + 5 cndmask (indices) + min/med3/med3
// (values) = 11 flat ops, dependency depth 2. Bit-equivalent to the
// sequential strict-< insert incl. earliest-index-wins on exact ties.
#define INS3F(d, h, B0, B1, B2, I0, I1, I2) do {                             \
    bool c0_ = (d) < (B0), c1_ = (d) < (B1), c2_ = (d) < (B2);               \
    int ni1_ = c0_ ? (I0) : (c1_ ? (h) : (I1));                              \
    int ni2_ = c1_ ? (I1) : (c2_ ? (h) : (I2));                              \
    I0 = c0_ ? (h) : (I0); I1 = ni1_; I2 = ni2_;                             \
    float nb1_ = __builtin_amdgcn_fmed3f(B0, B1, (d));                       \
    float nb2_ = __builtin_amdgcn_fmed3f(B1, B2, (d));                       \
    B0 = fminf(B0, (d)); B1 = nb1_; B2 = nb2_;                               \
} while (0)

// ---------------------------------------------------------------------------
// K1: prep.
//   [0,512):   fhT transpose (B,CH,NH) f32 -> (B,NH,CH) f16 (4 tiles each).
//   [512,896): W f32 -> f16.
// ---------------------------------------------------------------------------
__global__ __launch_bounds__(256) void prep_kernel(
    const float* __restrict__ feat_high, const float* __restrict__ Wm,
    f16* __restrict__ fhT, f16* __restrict__ Wh)
{
    __shared__ float tt[32][33];
    const int bid = blockIdx.x, tid = threadIdx.x;

    if (bid < 512) {
        const int tx = tid & 31, ty = tid >> 5;
        #pragma unroll
        for (int k = 0; k < 4; ++k) {
            const int u  = bid * 4 + k;            // 2048 tiles total
            const int ub = u >> 9, ut = u & 511;
            const int h0 = (ut & 63) * 32, c0 = (ut >> 6) * 32;
            #pragma unroll
            for (int pp = 0; pp < 4; ++pp)
                tt[ty + pp * 8][tx] =
                    feat_high[((size_t)ub * CH + c0 + ty + pp * 8) * NH + h0 + tx];
            __syncthreads();
            #pragma unroll
            for (int pp = 0; pp < 4; ++pp)
                fhT[((size_t)ub * NH + h0 + ty + pp * 8) * CH + c0 + tx] =
                    (f16)tt[tx][ty + pp * 8];
            __syncthreads();
        }
    } else {
        const int i = (bid - 512) * 256 + tid;     // 384 blocks
        Wh[i] = (f16)Wm[i];
    }
}

// ---------------------------------------------------------------------------
// K2: fused kNN + interp + GEMM. 512 blocks x 1024 thr (16 waves), 53.1 KB
// LDS -> 2 blocks/CU = 8 waves/SIMD.
// Phase A (knn): stage 2048 pts to LDS; wave w scans slice [w*128,+128) as
//   TWO 64-h chains per lane (same query; chain-B h-range entirely above
//   chain-A's -> slot-order 3-insert merge is exact). 2 independent dep
//   chains double ILP at unchanged occupancy/op-count. 48-way h-ascending
//   cross-wave merge -> weights. Bit-identical d2 + strict-< insert ==
//   reference top_k tie semantics.
// Phase B: interp gather -> As[64][392]; feat_low staged direct (coalesced).
// Phase C: barrier-free 12-kt MFMA K-loop (wave owns 16 o-rows; W from
//   L2-hot global); bias; per-block BN partials; yh f16 128B/row stores.
// ---------------------------------------------------------------------------
__global__ __launch_bounds__(1024, 8) void gemm_kernel(
    const float* __restrict__ xyz_low, const float* __restrict__ xyz_high,
    const float* __restrict__ feat_low, const f16* __restrict__ fhT,
    const f16* __restrict__ Wh, const float* __restrict__ bias,
    f16* __restrict__ yh, float* __restrict__ ps, float* __restrict__ psq)
{
    // As   [0,50176)      [64][392] f16 (gemm tile; Ys epilogue alias)
    // pts  [0,32768)      2048 float4   (dead before As written)
    // md   [32768,45312)  64*49 f32     (dead before As written)
    // mi   [45312,51584)  64*49 u16     (dead before As written)
    // idxL [51584,52352)  wL [52352,53120)   (live through gather)
    __shared__ __align__(16) char smraw[53120];
    f16*            As   = (f16*)smraw;
    float4*         pts  = (float4*)smraw;
    float*          md   = (float*)(smraw + 32768);
    unsigned short* mi   = (unsigned short*)(smraw + 45312);
    int*            idxL = (int*)(smraw + 51584);
    float*          wL   = (float*)(smraw + 52352);

    const int bid = blockIdx.x, tid = threadIdx.x;
    const int b = bid >> 7, l0 = (bid & 127) * 64;
    const int lane = tid & 63, w = tid >> 6;       // w = 0..15

    // ---- phase A: stage pts + dual-chain scan per wave-slice + merge ----
    {
        const float* xh = xyz_high + (size_t)b * NH * 3;
        #pragma unroll
        for (int k = 0; k < 2; ++k) {
            const int h = k * 1024 + tid;
            float x = xh[h * 3], yy = xh[h * 3 + 1], z = xh[h * 3 + 2];
            pts[h] = make_float4(x, yy, z, x * x + yy * yy + z * z);
        }
    }
    __syncthreads();
    {
        const float* xl = xyz_low + ((size_t)b * NL + l0 + lane) * 3;
        const float lx = xl[0], ly = xl[1], lz = xl[2];
        const float sl = lx * lx + ly * ly + lz * lz;

        float a0 = 1e30f, a1 = 1e30f, a2 = 1e30f;
        float c0 = 1e30f, c1 = 1e30f, c2 = 1e30f;
        int ia0 = 0, ia1 = 0, ia2 = 0, ic0 = 0, ic1 = 0, ic2 = 0;
        const int hA = w * 128, hB = hA + 64;
        #pragma unroll 8
        for (int i = 0; i < 64; ++i) {
            float4 pA = pts[hA + i];               // wave-uniform broadcast
            float4 pB = pts[hB + i];
            float dA = fmaf(-2.0f, fmaf(lx, pA.x, fmaf(ly, pA.y, lz * pA.z)),
                            sl + pA.w);
            float dB = fmaf(-2.0f, fmaf(lx, pB.x, fmaf(ly, pB.y, lz * pB.z)),
                            sl + pB.w);
            INS3F(dA, hA + i, a0, a1, a2, ia0, ia1, ia2);
            INS3F(dB, hB + i, c0, c1, c2, ic0, ic1, ic2);
        }
        // chain merge: B's h-range entirely above A's -> slot-order insert
        INS3F(c0, ic0, a0, a1, a2, ia0, ia1, ia2);
        INS3F(c1, ic1, a0, a1, a2, ia0, ia1, ia2);
        INS3F(c2, ic2, a0, a1, a2, ia0, ia1, ia2);
        const int cb = lane * 49 + w * 3;
        md[cb] = a0;     mi[cb] = (unsigned short)ia0;
        md[cb + 1] = a1; mi[cb + 1] = (unsigned short)ia1;
        md[cb + 2] = a2; mi[cb + 2] = (unsigned short)ia2;
    }
    __syncthreads();

    if (tid < 64) {   // 48-way merge in w-ascending (= h-ascending) order
        float e0 = 1e30f, e1 = 1e30f, e2 = 1e30f;
        int j0 = 0, j1 = 0, j2 = 0;
        #pragma unroll
        for (int q = 0; q < 48; ++q) {
            float d = md[tid * 49 + q];
            int  ii = mi[tid * 49 + q];
            INS3F(d, ii, e0, e1, e2, j0, j1, j2);
        }
        float d0 = sqrtf(fmaxf(e0, 0.0f));
        float d1 = sqrtf(fmaxf(e1, 0.0f));
        float d2f = sqrtf(fmaxf(e2, 0.0f));
        float iw0 = 1.0f / fmaxf(d0, 1e-8f);
        float iw1 = 1.0f / fmaxf(d1, 1e-8f);
        float iw2 = 1.0f / fmaxf(d2f, 1e-8f);
        float sum = iw0 + iw1 + iw2;
        idxL[tid] = j0; idxL[64 + tid] = j1; idxL[128 + tid] = j2;
        wL[tid] = iw0 / sum; wL[64 + tid] = iw1 / sum; wL[128 + tid] = iw2 / sum;
    }
    __syncthreads();

    // ---- phase B: interp gather + feat_low staging (pts/md/mi now dead) --
    {
        const int p = tid >> 4, q = tid & 15;      // 64 pts x 16-ch chunks
        const int j0 = idxL[p], j1 = idxL[64 + p], j2 = idxL[128 + p];
        const float u0 = wL[p], u1 = wL[64 + p], u2 = wL[128 + p];
        const f16* r0 = fhT + ((size_t)b * NH + j0) * CH + q * 16;
        const f16* r1 = fhT + ((size_t)b * NH + j1) * CH + q * 16;
        const f16* r2 = fhT + ((size_t)b * NH + j2) * CH + q * 16;
        #pragma unroll
        for (int j = 0; j < 2; ++j) {
            f16x8 v0 = *(const f16x8*)(r0 + j * 8);
            f16x8 v1 = *(const f16x8*)(r1 + j * 8);
            f16x8 v2 = *(const f16x8*)(r2 + j * 8);
            f16x8 o;
            #pragma unroll
            for (int e = 0; e < 8; ++e)
                o[e] = (f16)(u0 * (float)v0[e] + u1 * (float)v1[e]
                             + u2 * (float)v2[e]);
            *(f16x8*)&As[p * 392 + q * 16 + j * 8] = o;
        }
        // feat_low: l = tid&63 (coalesced), cq = tid>>6 (8 ch each)
        const int l = tid & 63, cq = tid >> 6;     // cq = 0..15
        const float* flb = feat_low + ((size_t)b * CL + cq * 8) * NL + l0 + l;
        f16 tmp[8];
        #pragma unroll
        for (int i = 0; i < 8; ++i)
            tmp[i] = (f16)flb[(size_t)i * NL];
        *(f16x8*)&As[l * 392 + 256 + cq * 8] = *(const f16x8*)&tmp[0];
    }
    __syncthreads();

    // ---- phase C: MFMA K-loop (wave owns 16 o-rows) + epilogue ----
    f32x4 acc[4] = {};
    const int kb = (lane >> 4) * 8;
    const int r  = lane & 15;
    #pragma unroll
    for (int kt = 0; kt < 12; ++kt) {
        const int k0 = kt * 32;
        f16x8 a = *(const f16x8*)&Wh[(size_t)(w * 16 + r) * CIN + k0 + kb];
        f16x8 bb[4];
        #pragma unroll
        for (int ni = 0; ni < 4; ++ni)
            bb[ni] = *(const f16x8*)&As[(ni * 16 + r) * 392 + k0 + kb];
        #pragma unroll
        for (int ni = 0; ni < 4; ++ni)
            acc[ni] = __builtin_amdgcn_mfma_f32_16x16x32_f16(
                a, bb[ni], acc[ni], 0, 0, 0);
    }

    const int r4 = (lane >> 4) * 4, cl = lane & 15;
    #pragma unroll
    for (int j = 0; j < 4; ++j) {
        const int o = w * 16 + r4 + j;
        const float bi = bias[o];
        float s = 0.0f, sq = 0.0f;
        #pragma unroll
        for (int ni = 0; ni < 4; ++ni) {
            acc[ni][j] += bi;
            float v = acc[ni][j];
            s += v; sq += v * v;
        }
        #pragma unroll
        for (int m = 1; m < 16; m <<= 1) {
            s  += __shfl_xor(s, m);
            sq += __shfl_xor(sq, m);
        }
        if (cl == 0) {
            ps [o * 512 + bid] = s;
            psq[o * 512 + bid] = sq;
        }
    }
    __syncthreads();   // all As reads done -> safe to alias with Ys

    f16* Ys = (f16*)smraw;             // [256][72] f16 = 36864 B
    #pragma unroll
    for (int j = 0; j < 4; ++j) {
        const int o = w * 16 + r4 + j;
        #pragma unroll
        for (int ni = 0; ni < 4; ++ni)
            Ys[o * 72 + cl + ni * 16] = (f16)acc[ni][j];
    }
    __syncthreads();
    {   // store: 4 threads per o-row -> 32B each, 128B contiguous per row
        const int o = tid >> 2, qtr = tid & 3;
        f16* dst = yh + ((size_t)b * COUT + o) * NL + l0 + qtr * 16;
        *(f16x8*)(dst)     = *(const f16x8*)&Ys[o * 72 + qtr * 16];
        *(f16x8*)(dst + 8) = *(const f16x8*)&Ys[o * 72 + qtr * 16 + 8];
    }
}

// ---------------------------------------------------------------------------
// K3: fused BN stats + apply + ReLU. Grid (COUT, B_): each block reduces its
// channel's 512 partials (deterministic, redundant across b-blocks) then
// applies to its (b,o) row of 8192.
// ---------------------------------------------------------------------------
__global__ __launch_bounds__(256) void stats_apply_kernel(
    const float* __restrict__ ps, const float* __restrict__ psq,
    const f16* __restrict__ yh,
    const float* __restrict__ gamma, const float* __restrict__ beta,
    float* __restrict__ y)
{
    const int o = blockIdx.x, b = blockIdx.y, tid = threadIdx.x;
    const int w = tid >> 6, lane = tid & 63;

    float s = ps[o * 512 + tid] + ps[o * 512 + 256 + tid];
    float q = psq[o * 512 + tid] + psq[o * 512 + 256 + tid];
    #pragma unroll
    for (int m = 32; m > 0; m >>= 1) {
        s += __shfl_down(s, m);
        q += __shfl_down(q, m);
    }
    __shared__ float red[8];
    if (lane == 0) { red[w] = s; red[4 + w] = q; }
    __syncthreads();
    s = red[0] + red[1] + red[2] + red[3];
    q = red[4] + red[5] + red[6] + red[7];
    const float n  = (float)(B_ * NL);
    const float mu = s / n;
    const float rs = rsqrtf(q / n - mu * mu + 1e-5f);
    const float g  = gamma[o], be = beta[o];

    const f16* src = yh + ((size_t)b * COUT + o) * NL;
    float*     dst = y  + ((size_t)b * COUT + o) * NL;
    #pragma unroll
    for (int it = 0; it < 4; ++it) {
        const int base = it * 2048 + tid * 8;
        f16x8 v = *(const f16x8*)(src + base);
        float4 o1, o2;
        o1.x = fmaxf(fmaf(g, ((float)v[0] - mu) * rs, be), 0.0f);
        o1.y = fmaxf(fmaf(g, ((float)v[1] - mu) * rs, be), 0.0f);
        o1.z = fmaxf(fmaf(g, ((float)v[2] - mu) * rs, be), 0.0f);
        o1.w = fmaxf(fmaf(g, ((float)v[3] - mu) * rs, be), 0.0f);
        o2.x = fmaxf(fmaf(g, ((float)v[4] - mu) * rs, be), 0.0f);
        o2.y = fmaxf(fmaf(g, ((float)v[5] - mu) * rs, be), 0.0f);
        o2.z = fmaxf(fmaf(g, ((float)v[6] - mu) * rs, be), 0.0f);
        o2.w = fmaxf(fmaf(g, ((float)v[7] - mu) * rs, be), 0.0f);
        *(float4*)(dst + base)     = o1;
        *(float4*)(dst + base + 4) = o2;
    }
}

// ---------------------------------------------------------------------------
extern "C" void kernel_launch(void* const* d_in, const int* in_sizes, int n_in,
                              void* d_out, int out_size, void* d_ws, size_t ws_size,
                              hipStream_t stream)
{
    const float* xyz_low   = (const float*)d_in[0];
    const float* xyz_high  = (const float*)d_in[1];
    const float* feat_low  = (const float*)d_in[2];
    const float* feat_high = (const float*)d_in[3];
    const float* Wm        = (const float*)d_in[4];
    const float* bias      = (const float*)d_in[5];
    const float* gamma     = (const float*)d_in[6];
    const float* beta      = (const float*)d_in[7];
    float* y = (float*)d_out;

    float* ps   = (float*)d_ws;                        // 256*512 f32
    float* psq  = ps + (size_t)COUT * 512;             // 256*512 f32
    f16*   Wh   = (f16*)(psq + (size_t)COUT * 512);    // 256*384 f16
    f16*   fhT  = Wh + (size_t)COUT * CIN;             // 4*2048*256 f16 (4.2MB)
    f16*   yh   = fhT + (size_t)B_ * NH * CH;          // 4*256*8192 f16 (16.8MB)

    prep_kernel<<<896, 256, 0, stream>>>(feat_high, Wm, fhT, Wh);
    gemm_kernel<<<512, 1024, 0, stream>>>(
        xyz_low, xyz_high, feat_low, fhT, Wh, bias, yh, ps, psq);
    stats_apply_kernel<<<dim3(COUT, B_), 256, 0, stream>>>(
        ps, psq, yh, gamma, beta, y);
}

// Round 20
// 66.866 us; speedup vs baseline: 1.2142x; 1.0979x over previous
//
#include <hip/hip_runtime.h>

constexpr int B_   = 4;
constexpr int NL   = 8192;
constexpr int NH   = 2048;
constexpr int CH   = 256;
constexpr int CL   = 128;
constexpr int CIN  = 384;
constexpr int COUT = 256;

typedef _Float16 f16;
typedef _Float16 f16x8 __attribute__((ext_vector_type(8)));
typedef float    f32x4 __attribute__((ext_vector_type(4)));

// Fast branchless top-3 insert: 3 cmp + 5 cndmask (indices) + min/med3/med3
// (values) = 11 flat ops, dependency depth 2. Bit-equivalent to the
// sequential strict-< insert incl. earliest-index-wins on exact ties.
#define INS3F(d, h, B0, B1, B2, I0, I1, I2) do {                             \
    bool c0_ = (d) < (B0), c1_ = (d) < (B1), c2_ = (d) < (B2);               \
    int ni1_ = c0_ ? (I0) : (c1_ ? (h) : (I1));                              \
    int ni2_ = c1_ ? (I1) : (c2_ ? (h) : (I2));                              \
    I0 = c0_ ? (h) : (I0); I1 = ni1_; I2 = ni2_;                             \
    float nb1_ = __builtin_amdgcn_fmed3f(B0, B1, (d));                       \
    float nb2_ = __builtin_amdgcn_fmed3f(B1, B2, (d));                       \
    B0 = fminf(B0, (d)); B1 = nb1_; B2 = nb2_;                               \
} while (0)

// ---------------------------------------------------------------------------
// K1: prep, one tile per block (max parallelism, no serial tile loop).
//   [0,2048):    fhT transpose (B,CH,NH) f32 -> (B,NH,CH) f16, 1 32x32 tile.
//   [2048,2432): W f32 -> f16.
// ---------------------------------------------------------------------------
__global__ __launch_bounds__(256) void prep_kernel(
    const float* __restrict__ feat_high, const float* __restrict__ Wm,
    f16* __restrict__ fhT, f16* __restrict__ Wh)
{
    __shared__ float tt[32][33];
    const int bid = blockIdx.x, tid = threadIdx.x;

    if (bid < 2048) {
        const int tx = tid & 31, ty = tid >> 5;
        const int ub = bid >> 9, ut = bid & 511;
        const int h0 = (ut & 63) * 32, c0 = (ut >> 6) * 32;
        #pragma unroll
        for (int pp = 0; pp < 4; ++pp)
            tt[ty + pp * 8][tx] =
                feat_high[((size_t)ub * CH + c0 + ty + pp * 8) * NH + h0 + tx];
        __syncthreads();
        #pragma unroll
        for (int pp = 0; pp < 4; ++pp)
            fhT[((size_t)ub * NH + h0 + ty + pp * 8) * CH + c0 + tx] =
                (f16)tt[tx][ty + pp * 8];
    } else {
        const int i = (bid - 2048) * 256 + tid;    // 384 blocks
        Wh[i] = (f16)Wm[i];
    }
}

// ---------------------------------------------------------------------------
// K2: fused kNN + interp + GEMM. 512 blocks x 1024 thr (16 waves), 53.1 KB
// LDS -> 2 blocks/CU = 8 waves/SIMD. (R17 configuration — best measured.)
// Phase A (knn): stage 2048 pts to LDS; wave w scans slice [w*128,+128)
//   (pts[h] wave-uniform -> LDS broadcast; lane = query point). 48-way
//   h-ascending merge -> weights. Bit-identical d2 + strict-< insert ==
//   reference top_k tie semantics.
// Phase B: interp gather -> As[64][392]; feat_low staged direct (coalesced).
// Phase C: barrier-free 12-kt MFMA K-loop (wave owns 16 o-rows; W from
//   L2-hot global); bias; per-block BN partials; yh f16 128B/row stores.
// ---------------------------------------------------------------------------
__global__ __launch_bounds__(1024, 8) void gemm_kernel(
    const float* __restrict__ xyz_low, const float* __restrict__ xyz_high,
    const float* __restrict__ feat_low, const f16* __restrict__ fhT,
    const f16* __restrict__ Wh, const float* __restrict__ bias,
    f16* __restrict__ yh, float* __restrict__ ps, float* __restrict__ psq)
{
    // As   [0,50176)      [64][392] f16 (gemm tile; Ys epilogue alias)
    // pts  [0,32768)      2048 float4   (dead before As written)
    // md   [32768,45312)  64*49 f32     (dead before As written)
    // mi   [45312,51584)  64*49 u16     (dead before As written)
    // idxL [51584,52352)  wL [52352,53120)   (live through gather)
    __shared__ __align__(16) char smraw[53120];
    f16*            As   = (f16*)smraw;
    float4*         pts  = (float4*)smraw;
    float*          md   = (float*)(smraw + 32768);
    unsigned short* mi   = (unsigned short*)(smraw + 45312);
    int*            idxL = (int*)(smraw + 51584);
    float*          wL   = (float*)(smraw + 52352);

    const int bid = blockIdx.x, tid = threadIdx.x;
    const int b = bid >> 7, l0 = (bid & 127) * 64;
    const int lane = tid & 63, w = tid >> 6;       // w = 0..15

    // ---- phase A: stage pts + 1-chain scan per wave-slice + merge ----
    {
        const float* xh = xyz_high + (size_t)b * NH * 3;
        #pragma unroll
        for (int k = 0; k < 2; ++k) {
            const int h = k * 1024 + tid;
            float x = xh[h * 3], yy = xh[h * 3 + 1], z = xh[h * 3 + 2];
            pts[h] = make_float4(x, yy, z, x * x + yy * yy + z * z);
        }
    }
    __syncthreads();
    {
        const float* xl = xyz_low + ((size_t)b * NL + l0 + lane) * 3;
        const float lx = xl[0], ly = xl[1], lz = xl[2];
        const float sl = lx * lx + ly * ly + lz * lz;

        float a0 = 1e30f, a1 = 1e30f, a2 = 1e30f;
        int ia0 = 0, ia1 = 0, ia2 = 0;
        const int h0 = w * 128;
        #pragma unroll 8
        for (int i = 0; i < 128; ++i) {
            float4 pA = pts[h0 + i];               // wave-uniform broadcast
            float dA = fmaf(-2.0f, fmaf(lx, pA.x, fmaf(ly, pA.y, lz * pA.z)),
                            sl + pA.w);
            INS3F(dA, h0 + i, a0, a1, a2, ia0, ia1, ia2);
        }
        const int cb = lane * 49 + w * 3;
        md[cb] = a0;     mi[cb] = (unsigned short)ia0;
        md[cb + 1] = a1; mi[cb + 1] = (unsigned short)ia1;
        md[cb + 2] = a2; mi[cb + 2] = (unsigned short)ia2;
    }
    __syncthreads();

    if (tid < 64) {   // 48-way merge in w-ascending (= h-ascending) order
        float e0 = 1e30f, e1 = 1e30f, e2 = 1e30f;
        int j0 = 0, j1 = 0, j2 = 0;
        #pragma unroll
        for (int q = 0; q < 48; ++q) {
            float d = md[tid * 49 + q];
            int  ii = mi[tid * 49 + q];
            INS3F(d, ii, e0, e1, e2, j0, j1, j2);
        }
        float d0 = sqrtf(fmaxf(e0, 0.0f));
        float d1 = sqrtf(fmaxf(e1, 0.0f));
        float d2f = sqrtf(fmaxf(e2, 0.0f));
        float iw0 = 1.0f / fmaxf(d0, 1e-8f);
        float iw1 = 1.0f / fmaxf(d1, 1e-8f);
        float iw2 = 1.0f / fmaxf(d2f, 1e-8f);
        float sum = iw0 + iw1 + iw2;
        idxL[tid] = j0; idxL[64 + tid] = j1; idxL[128 + tid] = j2;
        wL[tid] = iw0 / sum; wL[64 + tid] = iw1 / sum; wL[128 + tid] = iw2 / sum;
    }
    __syncthreads();

    // ---- phase B: interp gather + feat_low staging (pts/md/mi now dead) --
    {
        const int p = tid >> 4, q = tid & 15;      // 64 pts x 16-ch chunks
        const int j0 = idxL[p], j1 = idxL[64 + p], j2 = idxL[128 + p];
        const float u0 = wL[p], u1 = wL[64 + p], u2 = wL[128 + p];
        const f16* r0 = fhT + ((size_t)b * NH + j0) * CH + q * 16;
        const f16* r1 = fhT + ((size_t)b * NH + j1) * CH + q * 16;
        const f16* r2 = fhT + ((size_t)b * NH + j2) * CH + q * 16;
        #pragma unroll
        for (int j = 0; j < 2; ++j) {
            f16x8 v0 = *(const f16x8*)(r0 + j * 8);
            f16x8 v1 = *(const f16x8*)(r1 + j * 8);
            f16x8 v2 = *(const f16x8*)(r2 + j * 8);
            f16x8 o;
            #pragma unroll
            for (int e = 0; e < 8; ++e)
                o[e] = (f16)(u0 * (float)v0[e] + u1 * (float)v1[e]
                             + u2 * (float)v2[e]);
            *(f16x8*)&As[p * 392 + q * 16 + j * 8] = o;
        }
        // feat_low: l = tid&63 (coalesced), cq = tid>>6 (8 ch each)
        const int l = tid & 63, cq = tid >> 6;     // cq = 0..15
        const float* flb = feat_low + ((size_t)b * CL + cq * 8) * NL + l0 + l;
        f16 tmp[8];
        #pragma unroll
        for (int i = 0; i < 8; ++i)
            tmp[i] = (f16)flb[(size_t)i * NL];
        *(f16x8*)&As[l * 392 + 256 + cq * 8] = *(const f16x8*)&tmp[0];
    }
    __syncthreads();

    // ---- phase C: MFMA K-loop (wave owns 16 o-rows) + epilogue ----
    f32x4 acc[4] = {};
    const int kb = (lane >> 4) * 8;
    const int r  = lane & 15;
    #pragma unroll
    for (int kt = 0; kt < 12; ++kt) {
        const int k0 = kt * 32;
        f16x8 a = *(const f16x8*)&Wh[(size_t)(w * 16 + r) * CIN + k0 + kb];
        f16x8 bb[4];
        #pragma unroll
        for (int ni = 0; ni < 4; ++ni)
            bb[ni] = *(const f16x8*)&As[(ni * 16 + r) * 392 + k0 + kb];
        #pragma unroll
        for (int ni = 0; ni < 4; ++ni)
            acc[ni] = __builtin_amdgcn_mfma_f32_16x16x32_f16(
                a, bb[ni], acc[ni], 0, 0, 0);
    }

    const int r4 = (lane >> 4) * 4, cl = lane & 15;
    #pragma unroll
    for (int j = 0; j < 4; ++j) {
        const int o = w * 16 + r4 + j;
        const float bi = bias[o];
        float s = 0.0f, sq = 0.0f;
        #pragma unroll
        for (int ni = 0; ni < 4; ++ni) {
            acc[ni][j] += bi;
            float v = acc[ni][j];
            s += v; sq += v * v;
        }
        #pragma unroll
        for (int m = 1; m < 16; m <<= 1) {
            s  += __shfl_xor(s, m);
            sq += __shfl_xor(sq, m);
        }
        if (cl == 0) {
            ps [o * 512 + bid] = s;
            psq[o * 512 + bid] = sq;
        }
    }
    __syncthreads();   // all As reads done -> safe to alias with Ys

    f16* Ys = (f16*)smraw;             // [256][72] f16 = 36864 B
    #pragma unroll
    for (int j = 0; j < 4; ++j) {
        const int o = w * 16 + r4 + j;
        #pragma unroll
        for (int ni = 0; ni < 4; ++ni)
            Ys[o * 72 + cl + ni * 16] = (f16)acc[ni][j];
    }
    __syncthreads();
    {   // store: 4 threads per o-row -> 32B each, 128B contiguous per row
        const int o = tid >> 2, qtr = tid & 3;
        f16* dst = yh + ((size_t)b * COUT + o) * NL + l0 + qtr * 16;
        *(f16x8*)(dst)     = *(const f16x8*)&Ys[o * 72 + qtr * 16];
        *(f16x8*)(dst + 8) = *(const f16x8*)&Ys[o * 72 + qtr * 16 + 8];
    }
}

// ---------------------------------------------------------------------------
// K3: fused BN stats + apply + ReLU. Grid (COUT, B_): each block reduces its
// channel's 512 partials (deterministic, redundant across b-blocks) then
// applies to its (b,o) row of 8192.
// ---------------------------------------------------------------------------
__global__ __launch_bounds__(256) void stats_apply_kernel(
    const float* __restrict__ ps, const float* __restrict__ psq,
    const f16* __restrict__ yh,
    const float* __restrict__ gamma, const float* __restrict__ beta,
    float* __restrict__ y)
{
    const int o = blockIdx.x, b = blockIdx.y, tid = threadIdx.x;
    const int w = tid >> 6, lane = tid & 63;

    float s = ps[o * 512 + tid] + ps[o * 512 + 256 + tid];
    float q = psq[o * 512 + tid] + psq[o * 512 + 256 + tid];
    #pragma unroll
    for (int m = 32; m > 0; m >>= 1) {
        s += __shfl_down(s, m);
        q += __shfl_down(q, m);
    }
    __shared__ float red[8];
    if (lane == 0) { red[w] = s; red[4 + w] = q; }
    __syncthreads();
    s = red[0] + red[1] + red[2] + red[3];
    q = red[4] + red[5] + red[6] + red[7];
    const float n  = (float)(B_ * NL);
    const float mu = s / n;
    const float rs = rsqrtf(q / n - mu * mu + 1e-5f);
    const float g  = gamma[o], be = beta[o];

    const f16* src = yh + ((size_t)b * COUT + o) * NL;
    float*     dst = y  + ((size_t)b * COUT + o) * NL;
    #pragma unroll
    for (int it = 0; it < 4; ++it) {
        const int base = it * 2048 + tid * 8;
        f16x8 v = *(const f16x8*)(src + base);
        float4 o1, o2;
        o1.x = fmaxf(fmaf(g, ((float)v[0] - mu) * rs, be), 0.0f);
        o1.y = fmaxf(fmaf(g, ((float)v[1] - mu) * rs, be), 0.0f);
        o1.z = fmaxf(fmaf(g, ((float)v[2] - mu) * rs, be), 0.0f);
        o1.w = fmaxf(fmaf(g, ((float)v[3] - mu) * rs, be), 0.0f);
        o2.x = fmaxf(fmaf(g, ((float)v[4] - mu) * rs, be), 0.0f);
        o2.y = fmaxf(fmaf(g, ((float)v[5] - mu) * rs, be), 0.0f);
        o2.z = fmaxf(fmaf(g, ((float)v[6] - mu) * rs, be), 0.0f);
        o2.w = fmaxf(fmaf(g, ((float)v[7] - mu) * rs, be), 0.0f);
        *(float4*)(dst + base)     = o1;
        *(float4*)(dst + base + 4) = o2;
    }
}

// ---------------------------------------------------------------------------
extern "C" void kernel_launch(void* const* d_in, const int* in_sizes, int n_in,
                              void* d_out, int out_size, void* d_ws, size_t ws_size,
                              hipStream_t stream)
{
    const float* xyz_low   = (const float*)d_in[0];
    const float* xyz_high  = (const float*)d_in[1];
    const float* feat_low  = (const float*)d_in[2];
    const float* feat_high = (const float*)d_in[3];
    const float* Wm        = (const float*)d_in[4];
    const float* bias      = (const float*)d_in[5];
    const float* gamma     = (const float*)d_in[6];
    const float* beta      = (const float*)d_in[7];
    float* y = (float*)d_out;

    float* ps   = (float*)d_ws;                        // 256*512 f32
    float* psq  = ps + (size_t)COUT * 512;             // 256*512 f32
    f16*   Wh   = (f16*)(psq + (size_t)COUT * 512);    // 256*384 f16
    f16*   fhT  = Wh + (size_t)COUT * CIN;             // 4*2048*256 f16 (4.2MB)
    f16*   yh   = fhT + (size_t)B_ * NH * CH;          // 4*256*8192 f16 (16.8MB)

    prep_kernel<<<2432, 256, 0, stream>>>(feat_high, Wm, fhT, Wh);
    gemm_kernel<<<512, 1024, 0, stream>>>(
        xyz_low, xyz_high, feat_low, fhT, Wh, bias, yh, ps, psq);
    stats_apply_kernel<<<dim3(COUT, B_), 256, 0, stream>>>(
        ps, psq, yh, gamma, beta, y);
}